// Round 6
// baseline (1273.321 us; speedup 1.0000x reference)
//
#include <hip/hip_runtime.h>

#define NPTS   20000
#define NCHUNK 313   // ceil(NPTS/64)

typedef __bf16 bf16x8 __attribute__((ext_vector_type(8)));
typedef float  f32x4  __attribute__((ext_vector_type(4)));

__device__ __forceinline__ unsigned short f2b(float f) {
    __bf16 h = (__bf16)f;                       // RNE fptrunc (hw cvt on gfx950)
    union { __bf16 h; unsigned short s; } u; u.h = h; return u.s;
}
__device__ __forceinline__ unsigned int pk2(float a, float b) {
    return (unsigned int)f2b(a) | ((unsigned int)f2b(b) << 16);
}
// load 8 consecutive floats as two float4s, convert to bf16x8
__device__ __forceinline__ bf16x8 pack8v(const float* __restrict__ f) {
    f32x4 a = *(const f32x4*)(f);
    f32x4 c = *(const f32x4*)(f + 4);
    union { unsigned short s[8]; bf16x8 v; } u;
    #pragma unroll
    for (int i = 0; i < 4; ++i) u.s[i]     = f2b(a[i]);
    #pragma unroll
    for (int i = 0; i < 4; ++i) u.s[i + 4] = f2b(c[i]);
    return u.v;
}

// ---------------- workspace layout ----------------
// [0)        Xws      : 2048*768 fp32            = 6,291,456 B
// [6291456)  binned   : 40000 float4             =   640,000 B
// [6931456)  counts   : 1024 u32
// [6935552)  offsets  : 1024 u32
// [6939648)  cursors  : 1024 u32
#define WS_BINNED  6291456
#define WS_COUNTS  6931456
#define WS_OFFSETS 6935552
#define WS_CURSORS 6939648

// =============== kernel 0: zero counts/cursors (ws is poisoned each call) ===
__global__ void zero_kernel(unsigned int* __restrict__ counts,
                            unsigned int* __restrict__ cursors)
{
    int t = blockIdx.x * 256 + threadIdx.x;
    if (t < 1024) { counts[t] = 0; cursors[t] = 0; }
}

// =============== kernel 1: histogram points into 8^3 grid ==================
__global__ __launch_bounds__(256)
void count_kernel(const float* __restrict__ pointcloud,
                  unsigned int* __restrict__ counts)
{
    int t = blockIdx.x * 256 + threadIdx.x;
    if (t >= 2 * NPTS) return;
    int b = (t >= NPTS) ? 1 : 0;
    const float* p = pointcloud + t * 3;
    int cx = min(7, (int)(p[0] * 16.0f));
    int cy = min(7, (int)(p[1] * 16.0f));
    int cz = min(7, (int)(p[2] * 16.0f));
    int cid = (cz * 8 + cy) * 8 + cx;
    atomicAdd(&counts[b * 512 + cid], 1u);
}

// =============== kernel 2: exclusive prefix per batch ======================
__global__ __launch_bounds__(512)
void prefix_kernel(const unsigned int* __restrict__ counts,
                   unsigned int* __restrict__ offsets,
                   unsigned int* __restrict__ cursors)
{
    __shared__ unsigned int sdat[512];
    int b = blockIdx.x;
    int tid = threadIdx.x;
    unsigned int v = counts[b * 512 + tid];
    sdat[tid] = v;
    __syncthreads();
    #pragma unroll
    for (int off = 1; off < 512; off <<= 1) {
        unsigned int t = 0;
        if (tid >= off) t = sdat[tid - off];
        __syncthreads();
        sdat[tid] += t;
        __syncthreads();
    }
    unsigned int base = b * NPTS + (sdat[tid] - v);
    offsets[b * 512 + tid] = base;
    cursors[b * 512 + tid] = base;
}

// =============== kernel 3: scatter points into binned array ================
__global__ __launch_bounds__(256)
void scatter_kernel(const float* __restrict__ pointcloud,
                    unsigned int* __restrict__ cursors,
                    float4* __restrict__ binned)
{
    int t = blockIdx.x * 256 + threadIdx.x;
    if (t >= 2 * NPTS) return;
    int b = (t >= NPTS) ? 1 : 0;
    int i = t - b * NPTS;
    const float* p = pointcloud + t * 3;
    float x = p[0], y = p[1], z = p[2];
    int cx = min(7, (int)(x * 16.0f));
    int cy = min(7, (int)(y * 16.0f));
    int cz = min(7, (int)(z * 16.0f));
    int cid = (cz * 8 + cy) * 8 + cx;
    unsigned int slot = atomicAdd(&cursors[b * 512 + cid], 1u);
    binned[slot] = make_float4(x, y, z, __int_as_float(i));
}

// =============== kernel 4: per-seed masked select via grid =================
// A passing point has x in (-0.02,0.04), y^2+z^2 < 0.05^2  =>  |rel| < 0.0641.
// Conservative cell range: cells overlapping [s-0.066, s+0.066]^3 (margin 2e-3
// >> fp error). Mask itself is evaluated with the exact fp32 contract(off)
// arithmetic of the reference; bits set order-independently -> stage B
// (ordered first-64 extraction) semantics identical to the brute-force scan.
__global__ __launch_bounds__(256, 4)
void scan2_kernel(const float* __restrict__ seed_xyz,
                  const float* __restrict__ pointcloud,
                  const float* __restrict__ vp_rot,
                  const unsigned int* __restrict__ counts,
                  const unsigned int* __restrict__ offsets,
                  const float4* __restrict__ binned,
                  float* __restrict__ Xws)
{
    __shared__ unsigned int bm[4][640];     // 313 u64-words as u32 pairs
    __shared__ int idxs[4][64];
    __shared__ int cstart[27];
    __shared__ int ccnt[27];
    __shared__ int ccum[28];

    const int tid = threadIdx.x;
    const int wv  = tid >> 6;
    const int ln  = tid & 63;
    const int bs  = blockIdx.x;
    const int b   = bs >> 10;

    // zero bitmaps
    #pragma unroll
    for (int i = 0; i < 10; ++i) ((unsigned int*)bm)[tid + i * 256] = 0;

    const float sx = seed_xyz[bs*3+0];
    const float sy = seed_xyz[bs*3+1];
    const float sz = seed_xyz[bs*3+2];
    const float R00 = vp_rot[bs*9+0], R01 = vp_rot[bs*9+1], R02 = vp_rot[bs*9+2];
    const float R10 = vp_rot[bs*9+3], R11 = vp_rot[bs*9+4], R12 = vp_rot[bs*9+5];
    const float R20 = vp_rot[bs*9+6], R21 = vp_rot[bs*9+7], R22 = vp_rot[bs*9+8];

    // candidate cell range (uniform across block)
    const int lx = max(0, (int)floorf((sx - 0.066f) * 16.f));
    const int hx = min(7, (int)floorf((sx + 0.066f) * 16.f));
    const int ly = max(0, (int)floorf((sy - 0.066f) * 16.f));
    const int hy = min(7, (int)floorf((sy + 0.066f) * 16.f));
    const int lz = max(0, (int)floorf((sz - 0.066f) * 16.f));
    const int hz = min(7, (int)floorf((sz + 0.066f) * 16.f));
    const int nx = hx - lx + 1, ny = hy - ly + 1, nz = hz - lz + 1;
    const int ncell = nx * ny * nz;     // <= 27

    if (tid < ncell) {
        int cz = lz + tid / (nx * ny);
        int rem = tid % (nx * ny);
        int cy = ly + rem / nx;
        int cx = lx + rem % nx;
        int cid = (cz * 8 + cy) * 8 + cx;
        cstart[tid] = (int)offsets[b * 512 + cid];
        ccnt[tid]   = (int)counts [b * 512 + cid];
    }
    __syncthreads();
    if (wv == 0) {                      // wave-level prefix over <=27 cells
        int cnt = (ln < ncell) ? ccnt[ln] : 0;
        int incl = cnt;
        #pragma unroll
        for (int off = 1; off < 32; off <<= 1) {
            int t = __shfl_up(incl, off);
            if (ln >= off) incl += t;
        }
        if (ln < ncell) ccum[ln] = incl - cnt;
        if (ln == 31)   ccum[ncell] = incl;
    }
    __syncthreads();

    const int T = ccum[ncell];
    {
        #pragma clang fp contract(off)
        for (int i = tid; i < T; i += 256) {
            int k = 0;
            while (ccum[k + 1] <= i) ++k;
            float4 pt = binned[cstart[k] + (i - ccum[k])];
            float rx = pt.x - sx, ry = pt.y - sy, rz = pt.z - sz;
            float x = (rx*R00 + ry*R10) + rz*R20;
            float y = (rx*R01 + ry*R11) + rz*R21;
            float z = (rx*R02 + ry*R12) + rz*R22;
            bool mb = ((y*y + z*z) < 0.0025f) && (x > -0.02f);
            if (mb && (x < 0.04f)) {
                int n = __float_as_int(pt.w);
                unsigned int bit = 1u << (n & 31);
                int wi = n >> 5;
                if (x < 0.01f) atomicOr(&bm[0][wi], bit);
                if (x < 0.02f) atomicOr(&bm[1][wi], bit);
                if (x < 0.03f) atomicOr(&bm[2][wi], bit);
                atomicOr(&bm[3][wi], bit);
            }
        }
    }
    __syncthreads();

    // ---- stage B: ordered first-64 extraction (wave wv -> d=wv) ----
    {
        const int d = wv;
        int carry = 0;
        for (int r = 0; r < 5 && carry < 64; ++r) {
            int c = r*64 + ln;
            unsigned long long w = 0ULL;
            if (c < NCHUNK)
                w = ((unsigned long long)bm[d][2*c+1] << 32) | (unsigned long long)bm[d][2*c];
            int wc = __popcll(w);
            int incl = wc;
            #pragma unroll
            for (int off = 1; off < 64; off <<= 1) {
                int t = __shfl_up(incl, off);
                if (ln >= off) incl += t;
            }
            int rank  = carry + incl - wc;
            int total = __shfl(incl, 63);
            while (w && rank < 64) {
                int bp = __builtin_ctzll(w);
                w &= w - 1;
                idxs[d][rank] = c*64 + bp;
                ++rank;
            }
            carry += total;
        }
        int cnt = carry < 64 ? carry : 64;
        int first = (cnt > 0) ? idxs[d][0] : 0;
        if (ln >= cnt) idxs[d][ln] = first;
    }
    __syncthreads();

    // ---- gather: recompute rel_rot for selected points, store to ws ----
    {
        #pragma clang fp contract(off)
        int n = idxs[wv][ln];
        const float* p = pointcloud + (b*NPTS + n)*3;
        float rx = p[0] - sx, ry = p[1] - sy, rz = p[2] - sz;
        float x = (rx*R00 + ry*R10) + rz*R20;
        float y = (rx*R01 + ry*R11) + rz*R21;
        float z = (rx*R02 + ry*R12) + rz*R22;
        float* o = Xws + bs*768 + (wv*64 + ln)*3;
        o[0] = x; o[1] = y; o[2] = z;
    }
}

// ============================= kernel 5: MLP ==============================
// d-groups processed in pairs: N=128 per phase -> 7 barriers/block vs 13,
// double the MFMA per barrier.
struct __align__(16) SMemB {
    unsigned short h1[128][72];    // [sample][ch] +8 pad   18432 B
    unsigned short h2[128][136];   // [sample][ch] +8 pad   34816 B
    float  X[4][64][3];
    float2 sb2[128];
    float2 sb3[256];
    float  w1e[64][3];             // BN1 absorbed into layer-1 weights
    float  b1e[64];
};

// NOTE: min-waves MUST stay 2: (256,4) caps VGPR at 128 -> weight fragments
// spill -> ~1 GB scratch traffic (measured R4). (256,2) holds them in regs.
__global__ __launch_bounds__(256, 2)
void mlp_kernel(const float* __restrict__ Xws,
                const float* __restrict__ w1,
                const float* __restrict__ g1,  const float* __restrict__ be1,
                const float* __restrict__ mn1, const float* __restrict__ vr1,
                const float* __restrict__ w2,
                const float* __restrict__ g2,  const float* __restrict__ be2,
                const float* __restrict__ mn2, const float* __restrict__ vr2,
                const float* __restrict__ w3,
                const float* __restrict__ g3,  const float* __restrict__ be3,
                const float* __restrict__ mn3, const float* __restrict__ vr3,
                float* __restrict__ out)
{
    __shared__ SMemB sm;
    const int tid = threadIdx.x;
    const int wv  = tid >> 6;
    const int ln  = tid & 63;
    const int q   = ln >> 4;
    const int l15 = ln & 15;

    // XCD-aware swizzle: blocks writing the same output cache line (s..s+3)
    // share blk&7 -> same XCD under round-robin dispatch.
    const int blk = blockIdx.x;
    const int i8  = blk >> 3;
    const int s   = (blk & 7) * 128 + (i8 & 127);
    const int b   = i8 >> 7;
    const int bs  = b * 1024 + s;

    {
        float inv = g3[tid] / sqrtf(vr3[tid] + 1e-5f);
        sm.sb3[tid] = make_float2(inv, be3[tid] - mn3[tid] * inv);
    }
    if (tid < 128) {
        float inv = g2[tid] / sqrtf(vr2[tid] + 1e-5f);
        sm.sb2[tid] = make_float2(inv, be2[tid] - mn2[tid] * inv);
    }
    if (tid < 64) {
        float inv = g1[tid] / sqrtf(vr1[tid] + 1e-5f);
        sm.w1e[tid][0] = inv * w1[tid*3+0];
        sm.w1e[tid][1] = inv * w1[tid*3+1];
        sm.w1e[tid][2] = inv * w1[tid*3+2];
        sm.b1e[tid]    = be1[tid] - mn1[tid] * inv;
    }
    {
        const float* src = Xws + bs*768;
        float* dst = &sm.X[0][0][0];
        dst[tid]       = src[tid];
        dst[tid + 256] = src[tid + 256];
        dst[tid + 512] = src[tid + 512];
    }

    // weight A-fragments: A[m=lane&15][k=quad*8+j]
    bf16x8 aw2[2][2], aw3[4][4];
    #pragma unroll
    for (int m = 0; m < 2; ++m)
        #pragma unroll
        for (int kk = 0; kk < 2; ++kk)
            aw2[m][kk] = pack8v(w2 + ((wv*2+m)*16 + l15)*64 + kk*32 + q*8);
    #pragma unroll
    for (int m = 0; m < 4; ++m)
        #pragma unroll
        for (int kk = 0; kk < 4; ++kk)
            aw3[m][kk] = pack8v(w3 + ((wv*4+m)*16 + l15)*128 + kk*32 + q*8);

    __syncthreads();

    for (int pair = 0; pair < 2; ++pair) {
        // ---- layer 1: 128 samples (two d-groups), thread -> (half, sample j)
        {
            const int j    = tid & 127;         // sample row in h1
            const int half = tid >> 7;          // 32-channel half
            const int d    = pair*2 + (j >> 6);
            const int smp  = j & 63;
            float x0 = sm.X[d][smp][0];
            float x1 = sm.X[d][smp][1];
            float x2 = sm.X[d][smp][2];
            #pragma unroll
            for (int g = 0; g < 4; ++g) {
                uint4 u;
                unsigned int* up = &u.x;
                #pragma unroll
                for (int e = 0; e < 4; ++e) {
                    int ch = half*32 + g*8 + e*2;
                    float ha = fmaf(x0, sm.w1e[ch][0],
                               fmaf(x1, sm.w1e[ch][1],
                               fmaf(x2, sm.w1e[ch][2], sm.b1e[ch])));
                    float hb = fmaf(x0, sm.w1e[ch+1][0],
                               fmaf(x1, sm.w1e[ch+1][1],
                               fmaf(x2, sm.w1e[ch+1][2], sm.b1e[ch+1])));
                    up[e] = pk2(fmaxf(ha, 0.f), fmaxf(hb, 0.f));
                }
                *(uint4*)&sm.h1[j][half*32 + g*8] = u;
            }
        }
        __syncthreads();

        // ---- layer 2: M=128, K=64, N=128 (8 n-tiles)
        #pragma unroll
        for (int nt = 0; nt < 8; ++nt) {
            int n = nt*16 + l15;
            bf16x8 b0 = *(const bf16x8*)&sm.h1[n][q*8];
            bf16x8 b1 = *(const bf16x8*)&sm.h1[n][32 + q*8];
            #pragma unroll
            for (int m = 0; m < 2; ++m) {
                f32x4 acc = {0.f, 0.f, 0.f, 0.f};
                acc = __builtin_amdgcn_mfma_f32_16x16x32_bf16(aw2[m][0], b0, acc, 0, 0, 0);
                acc = __builtin_amdgcn_mfma_f32_16x16x32_bf16(aw2[m][1], b1, acc, 0, 0, 0);
                int ch0 = (wv*2+m)*16 + q*4;
                uint2 pkk;
                {
                    float2 sb0 = sm.sb2[ch0+0], sb1 = sm.sb2[ch0+1];
                    float2 sb2v = sm.sb2[ch0+2], sb3v = sm.sb2[ch0+3];
                    pkk.x = pk2(fmaxf(fmaf(acc[0], sb0.x, sb0.y), 0.f),
                                fmaxf(fmaf(acc[1], sb1.x, sb1.y), 0.f));
                    pkk.y = pk2(fmaxf(fmaf(acc[2], sb2v.x, sb2v.y), 0.f),
                                fmaxf(fmaf(acc[3], sb3v.x, sb3v.y), 0.f));
                }
                *(uint2*)&sm.h2[n][ch0] = pkk;
            }
        }
        __syncthreads();

        // ---- layer 3: M=256, K=128, N=128, fused BN+ReLU+max (per dd)
        {
            float rm[2][4][4];
            #pragma unroll
            for (int dd = 0; dd < 2; ++dd)
                #pragma unroll
                for (int m = 0; m < 4; ++m)
                    #pragma unroll
                    for (int r = 0; r < 4; ++r) rm[dd][m][r] = 0.f;

            #pragma unroll
            for (int nt = 0; nt < 8; ++nt) {
                const int dd = nt >> 2;
                int n = nt*16 + l15;
                bf16x8 bb0 = *(const bf16x8*)&sm.h2[n][ 0 + q*8];
                bf16x8 bb1 = *(const bf16x8*)&sm.h2[n][32 + q*8];
                bf16x8 bb2 = *(const bf16x8*)&sm.h2[n][64 + q*8];
                bf16x8 bb3 = *(const bf16x8*)&sm.h2[n][96 + q*8];
                #pragma unroll
                for (int m = 0; m < 4; ++m) {
                    f32x4 acc = {0.f, 0.f, 0.f, 0.f};
                    acc = __builtin_amdgcn_mfma_f32_16x16x32_bf16(aw3[m][0], bb0, acc, 0, 0, 0);
                    acc = __builtin_amdgcn_mfma_f32_16x16x32_bf16(aw3[m][1], bb1, acc, 0, 0, 0);
                    acc = __builtin_amdgcn_mfma_f32_16x16x32_bf16(aw3[m][2], bb2, acc, 0, 0, 0);
                    acc = __builtin_amdgcn_mfma_f32_16x16x32_bf16(aw3[m][3], bb3, acc, 0, 0, 0);
                    int ch0 = (wv*4+m)*16 + q*4;
                    #pragma unroll
                    for (int r = 0; r < 4; ++r) {
                        float2 sb = sm.sb3[ch0 + r];
                        float v = fmaxf(fmaf(acc[r], sb.x, sb.y), 0.f);
                        rm[dd][m][r] = fmaxf(rm[dd][m][r], v);
                    }
                }
            }
            #pragma unroll
            for (int dd = 0; dd < 2; ++dd)
                #pragma unroll
                for (int m = 0; m < 4; ++m)
                    #pragma unroll
                    for (int r = 0; r < 4; ++r) {
                        float v = rm[dd][m][r];
                        v = fmaxf(v, __shfl_xor(v, 1));
                        v = fmaxf(v, __shfl_xor(v, 2));
                        v = fmaxf(v, __shfl_xor(v, 4));
                        v = fmaxf(v, __shfl_xor(v, 8));
                        if (l15 == 0) {
                            int ch = (wv*4+m)*16 + q*4 + r;
                            out[((b*256 + ch)*1024 + s)*4 + pair*2 + dd] = v;
                        }
                    }
        }
        __syncthreads();
    }
}

extern "C" void kernel_launch(void* const* d_in, const int* in_sizes, int n_in,
                              void* d_out, int out_size, void* d_ws, size_t ws_size,
                              hipStream_t stream) {
    (void)in_sizes; (void)n_in; (void)out_size; (void)ws_size;
    const float* seed = (const float*)d_in[0];
    const float* pc   = (const float*)d_in[1];
    const float* rot  = (const float*)d_in[2];
    const float* w1   = (const float*)d_in[3];
    const float* g1   = (const float*)d_in[4];
    const float* be1  = (const float*)d_in[5];
    const float* mn1  = (const float*)d_in[6];
    const float* vr1  = (const float*)d_in[7];
    const float* w2   = (const float*)d_in[8];
    const float* g2   = (const float*)d_in[9];
    const float* be2  = (const float*)d_in[10];
    const float* mn2  = (const float*)d_in[11];
    const float* vr2  = (const float*)d_in[12];
    const float* w3   = (const float*)d_in[13];
    const float* g3   = (const float*)d_in[14];
    const float* be3  = (const float*)d_in[15];
    const float* mn3  = (const float*)d_in[16];
    const float* vr3  = (const float*)d_in[17];

    char* ws = (char*)d_ws;
    float*        Xws     = (float*)ws;
    float4*       binned  = (float4*)(ws + WS_BINNED);
    unsigned int* counts  = (unsigned int*)(ws + WS_COUNTS);
    unsigned int* offsets = (unsigned int*)(ws + WS_OFFSETS);
    unsigned int* cursors = (unsigned int*)(ws + WS_CURSORS);

    zero_kernel   <<<dim3(4),    dim3(256), 0, stream>>>(counts, cursors);
    count_kernel  <<<dim3(157),  dim3(256), 0, stream>>>(pc, counts);
    prefix_kernel <<<dim3(2),    dim3(512), 0, stream>>>(counts, offsets, cursors);
    scatter_kernel<<<dim3(157),  dim3(256), 0, stream>>>(pc, cursors, binned);
    scan2_kernel  <<<dim3(2048), dim3(256), 0, stream>>>(seed, pc, rot,
                                                         counts, offsets, binned, Xws);
    mlp_kernel    <<<dim3(2048), dim3(256), 0, stream>>>(
        Xws,
        w1, g1, be1, mn1, vr1,
        w2, g2, be2, mn2, vr2,
        w3, g3, be3, mn3, vr3,
        (float*)d_out);
}

// Round 8
// 254.468 us; speedup vs baseline: 5.0039x; 5.0039x over previous
//
#include <hip/hip_runtime.h>

#define NPTS   20000
#define NCHUNK 313   // ceil(NPTS/64)

typedef __bf16 bf16x8 __attribute__((ext_vector_type(8)));
typedef float  f32x4  __attribute__((ext_vector_type(4)));

__device__ __forceinline__ unsigned short f2b(float f) {
    __bf16 h = (__bf16)f;                       // RNE fptrunc (hw cvt on gfx950)
    union { __bf16 h; unsigned short s; } u; u.h = h; return u.s;
}
__device__ __forceinline__ unsigned int pk2(float a, float b) {
    return (unsigned int)f2b(a) | ((unsigned int)f2b(b) << 16);
}
// load 8 consecutive floats as two float4s, convert to bf16x8
__device__ __forceinline__ bf16x8 pack8v(const float* __restrict__ f) {
    f32x4 a = *(const f32x4*)(f);
    f32x4 c = *(const f32x4*)(f + 4);
    union { unsigned short s[8]; bf16x8 v; } u;
    #pragma unroll
    for (int i = 0; i < 4; ++i) u.s[i]     = f2b(a[i]);
    #pragma unroll
    for (int i = 0; i < 4; ++i) u.s[i + 4] = f2b(c[i]);
    return u.v;
}

// ---------------- workspace layout ----------------
#define WS_BINNED  6291456
#define WS_COUNTS  6931456
#define WS_OFFSETS 6935552
#define WS_CURSORS 6939648

// =============== kernel 0: zero counts/cursors (ws is poisoned each call) ===
__global__ void zero_kernel(unsigned int* __restrict__ counts,
                            unsigned int* __restrict__ cursors)
{
    int t = blockIdx.x * 256 + threadIdx.x;
    if (t < 1024) { counts[t] = 0; cursors[t] = 0; }
}

// =============== kernel 1: histogram points into 8^3 grid ==================
__global__ __launch_bounds__(256)
void count_kernel(const float* __restrict__ pointcloud,
                  unsigned int* __restrict__ counts)
{
    int t = blockIdx.x * 256 + threadIdx.x;
    if (t >= 2 * NPTS) return;
    int b = (t >= NPTS) ? 1 : 0;
    const float* p = pointcloud + t * 3;
    int cx = min(7, (int)(p[0] * 16.0f));
    int cy = min(7, (int)(p[1] * 16.0f));
    int cz = min(7, (int)(p[2] * 16.0f));
    int cid = (cz * 8 + cy) * 8 + cx;
    atomicAdd(&counts[b * 512 + cid], 1u);
}

// =============== kernel 2: exclusive prefix per batch ======================
__global__ __launch_bounds__(512)
void prefix_kernel(const unsigned int* __restrict__ counts,
                   unsigned int* __restrict__ offsets,
                   unsigned int* __restrict__ cursors)
{
    __shared__ unsigned int sdat[512];
    int b = blockIdx.x;
    int tid = threadIdx.x;
    unsigned int v = counts[b * 512 + tid];
    sdat[tid] = v;
    __syncthreads();
    #pragma unroll
    for (int off = 1; off < 512; off <<= 1) {
        unsigned int t = 0;
        if (tid >= off) t = sdat[tid - off];
        __syncthreads();
        sdat[tid] += t;
        __syncthreads();
    }
    unsigned int base = b * NPTS + (sdat[tid] - v);
    offsets[b * 512 + tid] = base;
    cursors[b * 512 + tid] = base;
}

// =============== kernel 3: scatter points into binned array ================
__global__ __launch_bounds__(256)
void scatter_kernel(const float* __restrict__ pointcloud,
                    unsigned int* __restrict__ cursors,
                    float4* __restrict__ binned)
{
    int t = blockIdx.x * 256 + threadIdx.x;
    if (t >= 2 * NPTS) return;
    int b = (t >= NPTS) ? 1 : 0;
    int i = t - b * NPTS;
    const float* p = pointcloud + t * 3;
    float x = p[0], y = p[1], z = p[2];
    int cx = min(7, (int)(x * 16.0f));
    int cy = min(7, (int)(y * 16.0f));
    int cz = min(7, (int)(z * 16.0f));
    int cid = (cz * 8 + cy) * 8 + cx;
    unsigned int slot = atomicAdd(&cursors[b * 512 + cid], 1u);
    binned[slot] = make_float4(x, y, z, __int_as_float(i));
}

// =============== kernel 4: per-seed masked select via grid =================
// Passing point: x in (-0.02,0.04), y^2+z^2 < 0.05^2  =>  |rel| < 0.0641.
// Conservative cell range: cells overlapping [s-0.066, s+0.066]^3.
// *** R7 post-mortem: a 2.112-cell-wide interval can straddle 4 cell
// boundaries -> nx,ny,nz up to 4 -> ncell up to 64 (NOT 27). The [27]
// arrays overflowed LDS; R6 survived by layout luck, R7 didn't. Arrays
// are now [64]. ***
// Mask uses exact fp32 contract(off) arithmetic; bits set order-independently
// -> stage B semantics identical to brute-force.
__global__ __launch_bounds__(256)
void scan2_kernel(const float* __restrict__ seed_xyz,
                  const float* __restrict__ pointcloud,
                  const float* __restrict__ vp_rot,
                  const unsigned int* __restrict__ counts,
                  const unsigned int* __restrict__ offsets,
                  const float4* __restrict__ binned,
                  float* __restrict__ Xws)
{
    __shared__ unsigned int bm[4][640];     // 313 u64-words as u32 pairs
    __shared__ int idxs[4][64];
    __shared__ int cstart[64];
    __shared__ int ccnt[64];

    const int tid = threadIdx.x;
    const int wv  = tid >> 6;
    const int ln  = tid & 63;
    const int bs  = blockIdx.x;
    const int b   = bs >> 10;

    // zero bitmaps
    #pragma unroll
    for (int i = 0; i < 10; ++i) ((unsigned int*)bm)[tid + i * 256] = 0;

    const float sx = seed_xyz[bs*3+0];
    const float sy = seed_xyz[bs*3+1];
    const float sz = seed_xyz[bs*3+2];
    const float R00 = vp_rot[bs*9+0], R01 = vp_rot[bs*9+1], R02 = vp_rot[bs*9+2];
    const float R10 = vp_rot[bs*9+3], R11 = vp_rot[bs*9+4], R12 = vp_rot[bs*9+5];
    const float R20 = vp_rot[bs*9+6], R21 = vp_rot[bs*9+7], R22 = vp_rot[bs*9+8];

    // candidate cell range (uniform across block), each dim spans 3 or 4 cells
    const int lx = max(0, (int)floorf((sx - 0.066f) * 16.f));
    const int hx = min(7, (int)floorf((sx + 0.066f) * 16.f));
    const int ly = max(0, (int)floorf((sy - 0.066f) * 16.f));
    const int hy = min(7, (int)floorf((sy + 0.066f) * 16.f));
    const int lz = max(0, (int)floorf((sz - 0.066f) * 16.f));
    const int hz = min(7, (int)floorf((sz + 0.066f) * 16.f));
    const int nx = hx - lx + 1, ny = hy - ly + 1, nz = hz - lz + 1;
    const int ncell = nx * ny * nz;     // <= 64

    if (tid < ncell) {
        int cz = lz + tid / (nx * ny);
        int rem = tid % (nx * ny);
        int cy = ly + rem / nx;
        int cx = lx + rem % nx;
        int cid = (cz * 8 + cy) * 8 + cx;
        cstart[tid] = (int)offsets[b * 512 + cid];
        ccnt[tid]   = (int)counts [b * 512 + cid];
    }
    __syncthreads();

    // cell-outer (wave wv takes cells wv, wv+4, ...), point-inner (strided)
    {
        #pragma clang fp contract(off)
        for (int k = wv; k < ncell; k += 4) {
            const int base = cstart[k];
            const int cnt  = ccnt[k];
            for (int i = ln; i < cnt; i += 64) {
                float4 pt = binned[base + i];
                float rx = pt.x - sx, ry = pt.y - sy, rz = pt.z - sz;
                float x = (rx*R00 + ry*R10) + rz*R20;
                float y = (rx*R01 + ry*R11) + rz*R21;
                float z = (rx*R02 + ry*R12) + rz*R22;
                if (((y*y + z*z) < 0.0025f) && (x > -0.02f) && (x < 0.04f)) {
                    int n = __float_as_int(pt.w);
                    unsigned int bit = 1u << (n & 31);
                    int wi = n >> 5;
                    if (x < 0.01f) atomicOr(&bm[0][wi], bit);
                    if (x < 0.02f) atomicOr(&bm[1][wi], bit);
                    if (x < 0.03f) atomicOr(&bm[2][wi], bit);
                    atomicOr(&bm[3][wi], bit);
                }
            }
        }
    }
    __syncthreads();

    // ---- stage B: ordered first-64 extraction (wave wv -> d=wv) ----
    {
        const int d = wv;
        int carry = 0;
        for (int r = 0; r < 5 && carry < 64; ++r) {
            int c = r*64 + ln;
            unsigned long long w = 0ULL;
            if (c < NCHUNK)
                w = ((unsigned long long)bm[d][2*c+1] << 32) | (unsigned long long)bm[d][2*c];
            int wc = __popcll(w);
            int incl = wc;
            #pragma unroll
            for (int off = 1; off < 64; off <<= 1) {
                int t = __shfl_up(incl, off);
                if (ln >= off) incl += t;
            }
            int rank  = carry + incl - wc;
            int total = __shfl(incl, 63);
            while (w && rank < 64) {
                int bp = __builtin_ctzll(w);
                w &= w - 1;
                idxs[d][rank] = c*64 + bp;
                ++rank;
            }
            carry += total;
        }
        int cnt = carry < 64 ? carry : 64;
        int first = (cnt > 0) ? idxs[d][0] : 0;
        if (ln >= cnt) idxs[d][ln] = first;
    }
    __syncthreads();

    // ---- gather: recompute rel_rot for selected points, store to ws ----
    {
        #pragma clang fp contract(off)
        int n = idxs[wv][ln];
        const float* p = pointcloud + (b*NPTS + n)*3;
        float rx = p[0] - sx, ry = p[1] - sy, rz = p[2] - sz;
        float x = (rx*R00 + ry*R10) + rz*R20;
        float y = (rx*R01 + ry*R11) + rz*R21;
        float z = (rx*R02 + ry*R12) + rz*R22;
        float* o = Xws + bs*768 + (wv*64 + ln)*3;
        o[0] = x; o[1] = y; o[2] = z;
    }
}

// ============================= kernel 5: MLP ==============================
// d-groups processed in pairs: N=128 per phase -> 7 barriers/block vs 13.
struct __align__(16) SMemB {
    unsigned short h1[128][72];    // [sample][ch] +8 pad   18432 B
    unsigned short h2[128][136];   // [sample][ch] +8 pad   34816 B
    float  X[4][64][3];
    float2 sb2[128];
    float2 sb3[256];
    float  w1e[64][3];             // BN1 absorbed into layer-1 weights
    float  b1e[64];
};

// NOTE: min-waves MUST stay 2: (256,4) caps VGPR at 128 -> weight fragments
// spill -> ~1 GB scratch traffic (measured R4). (256,2) holds them in regs.
__global__ __launch_bounds__(256, 2)
void mlp_kernel(const float* __restrict__ Xws,
                const float* __restrict__ w1,
                const float* __restrict__ g1,  const float* __restrict__ be1,
                const float* __restrict__ mn1, const float* __restrict__ vr1,
                const float* __restrict__ w2,
                const float* __restrict__ g2,  const float* __restrict__ be2,
                const float* __restrict__ mn2, const float* __restrict__ vr2,
                const float* __restrict__ w3,
                const float* __restrict__ g3,  const float* __restrict__ be3,
                const float* __restrict__ mn3, const float* __restrict__ vr3,
                float* __restrict__ out)
{
    __shared__ SMemB sm;
    const int tid = threadIdx.x;
    const int wv  = tid >> 6;
    const int ln  = tid & 63;
    const int q   = ln >> 4;
    const int l15 = ln & 15;

    // XCD-aware swizzle: blocks writing the same output cache line (s..s+3)
    // share blk&7 -> same XCD under round-robin dispatch.
    const int blk = blockIdx.x;
    const int i8  = blk >> 3;
    const int s   = (blk & 7) * 128 + (i8 & 127);
    const int b   = i8 >> 7;
    const int bs  = b * 1024 + s;

    {
        float inv = g3[tid] / sqrtf(vr3[tid] + 1e-5f);
        sm.sb3[tid] = make_float2(inv, be3[tid] - mn3[tid] * inv);
    }
    if (tid < 128) {
        float inv = g2[tid] / sqrtf(vr2[tid] + 1e-5f);
        sm.sb2[tid] = make_float2(inv, be2[tid] - mn2[tid] * inv);
    }
    if (tid < 64) {
        float inv = g1[tid] / sqrtf(vr1[tid] + 1e-5f);
        sm.w1e[tid][0] = inv * w1[tid*3+0];
        sm.w1e[tid][1] = inv * w1[tid*3+1];
        sm.w1e[tid][2] = inv * w1[tid*3+2];
        sm.b1e[tid]    = be1[tid] - mn1[tid] * inv;
    }
    {
        const float* src = Xws + bs*768;
        float* dst = &sm.X[0][0][0];
        dst[tid]       = src[tid];
        dst[tid + 256] = src[tid + 256];
        dst[tid + 512] = src[tid + 512];
    }

    // weight A-fragments: A[m=lane&15][k=quad*8+j]
    bf16x8 aw2[2][2], aw3[4][4];
    #pragma unroll
    for (int m = 0; m < 2; ++m)
        #pragma unroll
        for (int kk = 0; kk < 2; ++kk)
            aw2[m][kk] = pack8v(w2 + ((wv*2+m)*16 + l15)*64 + kk*32 + q*8);
    #pragma unroll
    for (int m = 0; m < 4; ++m)
        #pragma unroll
        for (int kk = 0; kk < 4; ++kk)
            aw3[m][kk] = pack8v(w3 + ((wv*4+m)*16 + l15)*128 + kk*32 + q*8);

    __syncthreads();

    for (int pair = 0; pair < 2; ++pair) {
        // ---- layer 1: 128 samples (two d-groups)
        {
            const int j    = tid & 127;
            const int half = tid >> 7;
            const int d    = pair*2 + (j >> 6);
            const int smp  = j & 63;
            float x0 = sm.X[d][smp][0];
            float x1 = sm.X[d][smp][1];
            float x2 = sm.X[d][smp][2];
            #pragma unroll
            for (int g = 0; g < 4; ++g) {
                uint4 u;
                unsigned int* up = &u.x;
                #pragma unroll
                for (int e = 0; e < 4; ++e) {
                    int ch = half*32 + g*8 + e*2;
                    float ha = fmaf(x0, sm.w1e[ch][0],
                               fmaf(x1, sm.w1e[ch][1],
                               fmaf(x2, sm.w1e[ch][2], sm.b1e[ch])));
                    float hb = fmaf(x0, sm.w1e[ch+1][0],
                               fmaf(x1, sm.w1e[ch+1][1],
                               fmaf(x2, sm.w1e[ch+1][2], sm.b1e[ch+1])));
                    up[e] = pk2(fmaxf(ha, 0.f), fmaxf(hb, 0.f));
                }
                *(uint4*)&sm.h1[j][half*32 + g*8] = u;
            }
        }
        __syncthreads();

        // ---- layer 2: M=128, K=64, N=128 (8 n-tiles)
        #pragma unroll
        for (int nt = 0; nt < 8; ++nt) {
            int n = nt*16 + l15;
            bf16x8 b0 = *(const bf16x8*)&sm.h1[n][q*8];
            bf16x8 b1 = *(const bf16x8*)&sm.h1[n][32 + q*8];
            #pragma unroll
            for (int m = 0; m < 2; ++m) {
                f32x4 acc = {0.f, 0.f, 0.f, 0.f};
                acc = __builtin_amdgcn_mfma_f32_16x16x32_bf16(aw2[m][0], b0, acc, 0, 0, 0);
                acc = __builtin_amdgcn_mfma_f32_16x16x32_bf16(aw2[m][1], b1, acc, 0, 0, 0);
                int ch0 = (wv*2+m)*16 + q*4;
                uint2 pkk;
                {
                    float2 sb0 = sm.sb2[ch0+0], sb1 = sm.sb2[ch0+1];
                    float2 sb2v = sm.sb2[ch0+2], sb3v = sm.sb2[ch0+3];
                    pkk.x = pk2(fmaxf(fmaf(acc[0], sb0.x, sb0.y), 0.f),
                                fmaxf(fmaf(acc[1], sb1.x, sb1.y), 0.f));
                    pkk.y = pk2(fmaxf(fmaf(acc[2], sb2v.x, sb2v.y), 0.f),
                                fmaxf(fmaf(acc[3], sb3v.x, sb3v.y), 0.f));
                }
                *(uint2*)&sm.h2[n][ch0] = pkk;
            }
        }
        __syncthreads();

        // ---- layer 3: M=256, K=128, N=128, fused BN+ReLU+max (per dd)
        {
            float rm[2][4][4];
            #pragma unroll
            for (int dd = 0; dd < 2; ++dd)
                #pragma unroll
                for (int m = 0; m < 4; ++m)
                    #pragma unroll
                    for (int r = 0; r < 4; ++r) rm[dd][m][r] = 0.f;

            #pragma unroll
            for (int nt = 0; nt < 8; ++nt) {
                const int dd = nt >> 2;
                int n = nt*16 + l15;
                bf16x8 bb0 = *(const bf16x8*)&sm.h2[n][ 0 + q*8];
                bf16x8 bb1 = *(const bf16x8*)&sm.h2[n][32 + q*8];
                bf16x8 bb2 = *(const bf16x8*)&sm.h2[n][64 + q*8];
                bf16x8 bb3 = *(const bf16x8*)&sm.h2[n][96 + q*8];
                #pragma unroll
                for (int m = 0; m < 4; ++m) {
                    f32x4 acc = {0.f, 0.f, 0.f, 0.f};
                    acc = __builtin_amdgcn_mfma_f32_16x16x32_bf16(aw3[m][0], bb0, acc, 0, 0, 0);
                    acc = __builtin_amdgcn_mfma_f32_16x16x32_bf16(aw3[m][1], bb1, acc, 0, 0, 0);
                    acc = __builtin_amdgcn_mfma_f32_16x16x32_bf16(aw3[m][2], bb2, acc, 0, 0, 0);
                    acc = __builtin_amdgcn_mfma_f32_16x16x32_bf16(aw3[m][3], bb3, acc, 0, 0, 0);
                    int ch0 = (wv*4+m)*16 + q*4;
                    #pragma unroll
                    for (int r = 0; r < 4; ++r) {
                        float2 sb = sm.sb3[ch0 + r];
                        float v = fmaxf(fmaf(acc[r], sb.x, sb.y), 0.f);
                        rm[dd][m][r] = fmaxf(rm[dd][m][r], v);
                    }
                }
            }
            #pragma unroll
            for (int dd = 0; dd < 2; ++dd)
                #pragma unroll
                for (int m = 0; m < 4; ++m)
                    #pragma unroll
                    for (int r = 0; r < 4; ++r) {
                        float v = rm[dd][m][r];
                        v = fmaxf(v, __shfl_xor(v, 1));
                        v = fmaxf(v, __shfl_xor(v, 2));
                        v = fmaxf(v, __shfl_xor(v, 4));
                        v = fmaxf(v, __shfl_xor(v, 8));
                        if (l15 == 0) {
                            int ch = (wv*4+m)*16 + q*4 + r;
                            out[((b*256 + ch)*1024 + s)*4 + pair*2 + dd] = v;
                        }
                    }
        }
        __syncthreads();
    }
}

extern "C" void kernel_launch(void* const* d_in, const int* in_sizes, int n_in,
                              void* d_out, int out_size, void* d_ws, size_t ws_size,
                              hipStream_t stream) {
    (void)in_sizes; (void)n_in; (void)out_size; (void)ws_size;
    const float* seed = (const float*)d_in[0];
    const float* pc   = (const float*)d_in[1];
    const float* rot  = (const float*)d_in[2];
    const float* w1   = (const float*)d_in[3];
    const float* g1   = (const float*)d_in[4];
    const float* be1  = (const float*)d_in[5];
    const float* mn1  = (const float*)d_in[6];
    const float* vr1  = (const float*)d_in[7];
    const float* w2   = (const float*)d_in[8];
    const float* g2   = (const float*)d_in[9];
    const float* be2  = (const float*)d_in[10];
    const float* mn2  = (const float*)d_in[11];
    const float* vr2  = (const float*)d_in[12];
    const float* w3   = (const float*)d_in[13];
    const float* g3   = (const float*)d_in[14];
    const float* be3  = (const float*)d_in[15];
    const float* mn3  = (const float*)d_in[16];
    const float* vr3  = (const float*)d_in[17];

    char* ws = (char*)d_ws;
    float*        Xws     = (float*)ws;
    float4*       binned  = (float4*)(ws + WS_BINNED);
    unsigned int* counts  = (unsigned int*)(ws + WS_COUNTS);
    unsigned int* offsets = (unsigned int*)(ws + WS_OFFSETS);
    unsigned int* cursors = (unsigned int*)(ws + WS_CURSORS);

    zero_kernel   <<<dim3(4),    dim3(256), 0, stream>>>(counts, cursors);
    count_kernel  <<<dim3(157),  dim3(256), 0, stream>>>(pc, counts);
    prefix_kernel <<<dim3(2),    dim3(512), 0, stream>>>(counts, offsets, cursors);
    scatter_kernel<<<dim3(157),  dim3(256), 0, stream>>>(pc, cursors, binned);
    scan2_kernel  <<<dim3(2048), dim3(256), 0, stream>>>(seed, pc, rot,
                                                         counts, offsets, binned, Xws);
    mlp_kernel    <<<dim3(2048), dim3(256), 0, stream>>>(
        Xws,
        w1, g1, be1, mn1, vr1,
        w2, g2, be2, mn2, vr2,
        w3, g3, be3, mn3, vr3,
        (float*)d_out);
}

// Round 9
// 243.437 us; speedup vs baseline: 5.2306x; 1.0453x over previous
//
#include <hip/hip_runtime.h>

#define NPTS   20000
#define NCHUNK 313   // ceil(NPTS/64)

typedef __bf16 bf16x8 __attribute__((ext_vector_type(8)));
typedef float  f32x4  __attribute__((ext_vector_type(4)));

__device__ __forceinline__ unsigned short f2b(float f) {
    __bf16 h = (__bf16)f;                       // RNE fptrunc (hw cvt on gfx950)
    union { __bf16 h; unsigned short s; } u; u.h = h; return u.s;
}
__device__ __forceinline__ unsigned int pk2(float a, float b) {
    return (unsigned int)f2b(a) | ((unsigned int)f2b(b) << 16);
}
// load 8 consecutive floats as two float4s, convert to bf16x8
__device__ __forceinline__ bf16x8 pack8v(const float* __restrict__ f) {
    f32x4 a = *(const f32x4*)(f);
    f32x4 c = *(const f32x4*)(f + 4);
    union { unsigned short s[8]; bf16x8 v; } u;
    #pragma unroll
    for (int i = 0; i < 4; ++i) u.s[i]     = f2b(a[i]);
    #pragma unroll
    for (int i = 0; i < 4; ++i) u.s[i + 4] = f2b(c[i]);
    return u.v;
}

// ---------------- workspace layout ----------------
#define WS_BINNED  0
#define WS_COUNTS  640000
#define WS_OFFSETS 644096
#define WS_CURSORS 648192

// =============== kernel 0: zero counts/cursors (ws is poisoned each call) ===
__global__ void zero_kernel(unsigned int* __restrict__ counts,
                            unsigned int* __restrict__ cursors)
{
    int t = blockIdx.x * 256 + threadIdx.x;
    if (t < 1024) { counts[t] = 0; cursors[t] = 0; }
}

// =============== kernel 1: histogram points into 8^3 grid ==================
__global__ __launch_bounds__(256)
void count_kernel(const float* __restrict__ pointcloud,
                  unsigned int* __restrict__ counts)
{
    int t = blockIdx.x * 256 + threadIdx.x;
    if (t >= 2 * NPTS) return;
    int b = (t >= NPTS) ? 1 : 0;
    const float* p = pointcloud + t * 3;
    int cx = min(7, (int)(p[0] * 16.0f));
    int cy = min(7, (int)(p[1] * 16.0f));
    int cz = min(7, (int)(p[2] * 16.0f));
    int cid = (cz * 8 + cy) * 8 + cx;
    atomicAdd(&counts[b * 512 + cid], 1u);
}

// =============== kernel 2: exclusive prefix per batch ======================
__global__ __launch_bounds__(512)
void prefix_kernel(const unsigned int* __restrict__ counts,
                   unsigned int* __restrict__ offsets,
                   unsigned int* __restrict__ cursors)
{
    __shared__ unsigned int sdat[512];
    int b = blockIdx.x;
    int tid = threadIdx.x;
    unsigned int v = counts[b * 512 + tid];
    sdat[tid] = v;
    __syncthreads();
    #pragma unroll
    for (int off = 1; off < 512; off <<= 1) {
        unsigned int t = 0;
        if (tid >= off) t = sdat[tid - off];
        __syncthreads();
        sdat[tid] += t;
        __syncthreads();
    }
    unsigned int base = b * NPTS + (sdat[tid] - v);
    offsets[b * 512 + tid] = base;
    cursors[b * 512 + tid] = base;
}

// =============== kernel 3: scatter points into binned array ================
__global__ __launch_bounds__(256)
void scatter_kernel(const float* __restrict__ pointcloud,
                    unsigned int* __restrict__ cursors,
                    float4* __restrict__ binned)
{
    int t = blockIdx.x * 256 + threadIdx.x;
    if (t >= 2 * NPTS) return;
    int b = (t >= NPTS) ? 1 : 0;
    int i = t - b * NPTS;
    const float* p = pointcloud + t * 3;
    float x = p[0], y = p[1], z = p[2];
    int cx = min(7, (int)(x * 16.0f));
    int cy = min(7, (int)(y * 16.0f));
    int cz = min(7, (int)(z * 16.0f));
    int cid = (cz * 8 + cy) * 8 + cx;
    unsigned int slot = atomicAdd(&cursors[b * 512 + cid], 1u);
    binned[slot] = make_float4(x, y, z, __int_as_float(i));
}

// =============== kernel 4: FUSED grid-scan + MLP ===========================
// Scan bitmap/cell arrays are dead after stage B -> union with h1/h2 so LDS
// stays ~34.9 KB (4 blocks/CU, the R5 sweet spot). mlp phases are R5's
// proven unpaired form (R8 pairing cut blocks/CU 4->2 and regressed).
struct __align__(16) SMemF {
    union {
        struct {
            unsigned int bm[4][640];    // 10240 B: 313 u64-words as u32 pairs
            int cstart[64];             // 256 B (ncell can reach 64! R7 bug)
            int ccnt[64];               // 256 B
        } a;
        struct {
            unsigned short h1[64][72];  //  9216 B [sample][ch] +8 pad
            unsigned short h2[64][136]; // 17408 B [sample][ch] +8 pad
        } b;
    } u;
    int    idxs[4][64];
    float  X[4][64][3];
    float2 sb2[128];
    float2 sb3[256];
    float  w1e[64][3];                  // BN1 absorbed into layer-1 weights
    float  b1e[64];
};

// NOTE: min-waves MUST stay 2: (256,4) caps VGPR at 128 -> weight fragments
// spill -> ~1 GB scratch traffic (measured R4). (256,2) holds them in regs.
__global__ __launch_bounds__(256, 2)
void fused_kernel(const float* __restrict__ seed_xyz,
                  const float* __restrict__ pointcloud,
                  const float* __restrict__ vp_rot,
                  const unsigned int* __restrict__ counts,
                  const unsigned int* __restrict__ offsets,
                  const float4* __restrict__ binned,
                  const float* __restrict__ w1,
                  const float* __restrict__ g1,  const float* __restrict__ be1,
                  const float* __restrict__ mn1, const float* __restrict__ vr1,
                  const float* __restrict__ w2,
                  const float* __restrict__ g2,  const float* __restrict__ be2,
                  const float* __restrict__ mn2, const float* __restrict__ vr2,
                  const float* __restrict__ w3,
                  const float* __restrict__ g3,  const float* __restrict__ be3,
                  const float* __restrict__ mn3, const float* __restrict__ vr3,
                  float* __restrict__ out)
{
    __shared__ SMemF sm;
    const int tid = threadIdx.x;
    const int wv  = tid >> 6;
    const int ln  = tid & 63;
    const int q   = ln >> 4;
    const int l15 = ln & 15;

    // XCD-aware swizzle: blocks writing the same output cache line (s..s+3)
    // share blk&7 -> same XCD under round-robin dispatch.
    const int blk = blockIdx.x;
    const int i8  = blk >> 3;
    const int s   = (blk & 7) * 128 + (i8 & 127);
    const int b   = i8 >> 7;
    const int bs  = b * 1024 + s;

    // ---- BN constants / absorbed layer-1 weights ----
    {
        float inv = g3[tid] / sqrtf(vr3[tid] + 1e-5f);
        sm.sb3[tid] = make_float2(inv, be3[tid] - mn3[tid] * inv);
    }
    if (tid < 128) {
        float inv = g2[tid] / sqrtf(vr2[tid] + 1e-5f);
        sm.sb2[tid] = make_float2(inv, be2[tid] - mn2[tid] * inv);
    }
    if (tid < 64) {
        float inv = g1[tid] / sqrtf(vr1[tid] + 1e-5f);
        sm.w1e[tid][0] = inv * w1[tid*3+0];
        sm.w1e[tid][1] = inv * w1[tid*3+1];
        sm.w1e[tid][2] = inv * w1[tid*3+2];
        sm.b1e[tid]    = be1[tid] - mn1[tid] * inv;
    }

    // ---- zero bitmaps (2560 u32 = bm[4][640]) ----
    {
        unsigned int* bmp = &sm.u.a.bm[0][0];
        #pragma unroll
        for (int i = 0; i < 10; ++i) bmp[tid + i * 256] = 0;
    }

    const float sx = seed_xyz[bs*3+0];
    const float sy = seed_xyz[bs*3+1];
    const float sz = seed_xyz[bs*3+2];
    const float R00 = vp_rot[bs*9+0], R01 = vp_rot[bs*9+1], R02 = vp_rot[bs*9+2];
    const float R10 = vp_rot[bs*9+3], R11 = vp_rot[bs*9+4], R12 = vp_rot[bs*9+5];
    const float R20 = vp_rot[bs*9+6], R21 = vp_rot[bs*9+7], R22 = vp_rot[bs*9+8];

    // candidate cell range: cells overlapping [s-0.066, s+0.066]^3
    // (each dim spans 3 OR 4 cells -> ncell up to 64; R7 post-mortem)
    const int lx = max(0, (int)floorf((sx - 0.066f) * 16.f));
    const int hx = min(7, (int)floorf((sx + 0.066f) * 16.f));
    const int ly = max(0, (int)floorf((sy - 0.066f) * 16.f));
    const int hy = min(7, (int)floorf((sy + 0.066f) * 16.f));
    const int lz = max(0, (int)floorf((sz - 0.066f) * 16.f));
    const int hz = min(7, (int)floorf((sz + 0.066f) * 16.f));
    const int nx = hx - lx + 1, ny = hy - ly + 1, nz = hz - lz + 1;
    const int ncell = nx * ny * nz;     // <= 64

    if (tid < ncell) {
        int cz = lz + tid / (nx * ny);
        int rem = tid % (nx * ny);
        int cy = ly + rem / nx;
        int cx = lx + rem % nx;
        int cid = (cz * 8 + cy) * 8 + cx;
        sm.u.a.cstart[tid] = (int)offsets[b * 512 + cid];
        sm.u.a.ccnt[tid]   = (int)counts [b * 512 + cid];
    }
    __syncthreads();

    // ---- scan: cell-outer (wave wv takes cells wv, wv+4, ...), point-inner.
    // Mask uses exact fp32 contract(off) arithmetic; bits set order-
    // independently -> stage B semantics identical to brute-force.
    {
        #pragma clang fp contract(off)
        for (int k = wv; k < ncell; k += 4) {
            const int base = sm.u.a.cstart[k];
            const int cnt  = sm.u.a.ccnt[k];
            for (int i = ln; i < cnt; i += 64) {
                float4 pt = binned[base + i];
                float rx = pt.x - sx, ry = pt.y - sy, rz = pt.z - sz;
                float x = (rx*R00 + ry*R10) + rz*R20;
                float y = (rx*R01 + ry*R11) + rz*R21;
                float z = (rx*R02 + ry*R12) + rz*R22;
                if (((y*y + z*z) < 0.0025f) && (x > -0.02f) && (x < 0.04f)) {
                    int n = __float_as_int(pt.w);
                    unsigned int bit = 1u << (n & 31);
                    int wi = n >> 5;
                    if (x < 0.01f) atomicOr(&sm.u.a.bm[0][wi], bit);
                    if (x < 0.02f) atomicOr(&sm.u.a.bm[1][wi], bit);
                    if (x < 0.03f) atomicOr(&sm.u.a.bm[2][wi], bit);
                    atomicOr(&sm.u.a.bm[3][wi], bit);
                }
            }
        }
    }
    __syncthreads();

    // ---- stage B: ordered first-64 extraction (wave wv -> d=wv) ----
    {
        const int d = wv;
        int carry = 0;
        for (int r = 0; r < 5 && carry < 64; ++r) {
            int c = r*64 + ln;
            unsigned long long w = 0ULL;
            if (c < NCHUNK)
                w = ((unsigned long long)sm.u.a.bm[d][2*c+1] << 32)
                  |  (unsigned long long)sm.u.a.bm[d][2*c];
            int wc = __popcll(w);
            int incl = wc;
            #pragma unroll
            for (int off = 1; off < 64; off <<= 1) {
                int t = __shfl_up(incl, off);
                if (ln >= off) incl += t;
            }
            int rank  = carry + incl - wc;
            int total = __shfl(incl, 63);
            while (w && rank < 64) {
                int bp = __builtin_ctzll(w);
                w &= w - 1;
                sm.idxs[d][rank] = c*64 + bp;
                ++rank;
            }
            carry += total;
        }
        int cnt = carry < 64 ? carry : 64;
        int first = (cnt > 0) ? sm.idxs[d][0] : 0;
        if (ln >= cnt) sm.idxs[d][ln] = first;
    }
    __syncthreads();

    // ---- gather: recompute rel_rot (fp32, contract off) -> X in LDS ----
    {
        #pragma clang fp contract(off)
        int n = sm.idxs[wv][ln];
        const float* p = pointcloud + (b*NPTS + n)*3;
        float rx = p[0] - sx, ry = p[1] - sy, rz = p[2] - sz;
        sm.X[wv][ln][0] = (rx*R00 + ry*R10) + rz*R20;
        sm.X[wv][ln][1] = (rx*R01 + ry*R11) + rz*R21;
        sm.X[wv][ln][2] = (rx*R02 + ry*R12) + rz*R22;
    }

    // ---- weight A-fragments: A[m=lane&15][k=quad*8+j] ----
    bf16x8 aw2[2][2], aw3[4][4];
    #pragma unroll
    for (int m = 0; m < 2; ++m)
        #pragma unroll
        for (int kk = 0; kk < 2; ++kk)
            aw2[m][kk] = pack8v(w2 + ((wv*2+m)*16 + l15)*64 + kk*32 + q*8);
    #pragma unroll
    for (int m = 0; m < 4; ++m)
        #pragma unroll
        for (int kk = 0; kk < 4; ++kk)
            aw3[m][kk] = pack8v(w3 + ((wv*4+m)*16 + l15)*128 + kk*32 + q*8);

    __syncthreads();    // X visible; bm/cstart/ccnt dead -> h1/h2 may reuse

    // ---- MLP + max, one d-group (64 samples) at a time (R5 proven form) ----
    for (int d = 0; d < 4; ++d) {
        // layer 1 (fma-only, BN absorbed): thread -> sample ln, ch wv*16..+15
        {
            float x0 = sm.X[d][ln][0];
            float x1 = sm.X[d][ln][1];
            float x2 = sm.X[d][ln][2];
            unsigned int pk[8];
            #pragma unroll
            for (int i = 0; i < 8; ++i) {
                int ch = wv*16 + i*2;
                float ha = fmaf(x0, sm.w1e[ch][0],
                           fmaf(x1, sm.w1e[ch][1],
                           fmaf(x2, sm.w1e[ch][2], sm.b1e[ch])));
                float hb = fmaf(x0, sm.w1e[ch+1][0],
                           fmaf(x1, sm.w1e[ch+1][1],
                           fmaf(x2, sm.w1e[ch+1][2], sm.b1e[ch+1])));
                pk[i] = pk2(fmaxf(ha, 0.f), fmaxf(hb, 0.f));
            }
            uint4 u0 = make_uint4(pk[0], pk[1], pk[2], pk[3]);
            uint4 u1 = make_uint4(pk[4], pk[5], pk[6], pk[7]);
            *(uint4*)&sm.u.b.h1[ln][wv*16 + 0] = u0;
            *(uint4*)&sm.u.b.h1[ln][wv*16 + 8] = u1;
        }
        __syncthreads();

        // layer 2: M=128 (wave owns 2 M-tiles), K=64, N=64
        #pragma unroll
        for (int nt = 0; nt < 4; ++nt) {
            int n = nt*16 + l15;
            bf16x8 b0 = *(const bf16x8*)&sm.u.b.h1[n][q*8];
            bf16x8 b1 = *(const bf16x8*)&sm.u.b.h1[n][32 + q*8];
            #pragma unroll
            for (int m = 0; m < 2; ++m) {
                f32x4 acc = {0.f, 0.f, 0.f, 0.f};
                acc = __builtin_amdgcn_mfma_f32_16x16x32_bf16(aw2[m][0], b0, acc, 0, 0, 0);
                acc = __builtin_amdgcn_mfma_f32_16x16x32_bf16(aw2[m][1], b1, acc, 0, 0, 0);
                int ch0 = (wv*2+m)*16 + q*4;
                float2 sb0 = sm.sb2[ch0+0], sb1 = sm.sb2[ch0+1];
                float2 sb2v = sm.sb2[ch0+2], sb3v = sm.sb2[ch0+3];
                uint2 pkk;
                pkk.x = pk2(fmaxf(fmaf(acc[0], sb0.x, sb0.y), 0.f),
                            fmaxf(fmaf(acc[1], sb1.x, sb1.y), 0.f));
                pkk.y = pk2(fmaxf(fmaf(acc[2], sb2v.x, sb2v.y), 0.f),
                            fmaxf(fmaf(acc[3], sb3v.x, sb3v.y), 0.f));
                *(uint2*)&sm.u.b.h2[n][ch0] = pkk;
            }
        }
        __syncthreads();

        // layer 3: M=256 (wave owns 4 M-tiles), K=128, fused BN+ReLU+max
        {
            float rm[4][4];
            #pragma unroll
            for (int m = 0; m < 4; ++m)
                #pragma unroll
                for (int r = 0; r < 4; ++r) rm[m][r] = 0.f;

            #pragma unroll
            for (int nt = 0; nt < 4; ++nt) {
                int n = nt*16 + l15;
                bf16x8 bb0 = *(const bf16x8*)&sm.u.b.h2[n][ 0 + q*8];
                bf16x8 bb1 = *(const bf16x8*)&sm.u.b.h2[n][32 + q*8];
                bf16x8 bb2 = *(const bf16x8*)&sm.u.b.h2[n][64 + q*8];
                bf16x8 bb3 = *(const bf16x8*)&sm.u.b.h2[n][96 + q*8];
                #pragma unroll
                for (int m = 0; m < 4; ++m) {
                    f32x4 acc = {0.f, 0.f, 0.f, 0.f};
                    acc = __builtin_amdgcn_mfma_f32_16x16x32_bf16(aw3[m][0], bb0, acc, 0, 0, 0);
                    acc = __builtin_amdgcn_mfma_f32_16x16x32_bf16(aw3[m][1], bb1, acc, 0, 0, 0);
                    acc = __builtin_amdgcn_mfma_f32_16x16x32_bf16(aw3[m][2], bb2, acc, 0, 0, 0);
                    acc = __builtin_amdgcn_mfma_f32_16x16x32_bf16(aw3[m][3], bb3, acc, 0, 0, 0);
                    int ch0 = (wv*4+m)*16 + q*4;
                    #pragma unroll
                    for (int r = 0; r < 4; ++r) {
                        float2 sb = sm.sb3[ch0 + r];
                        float v = fmaxf(fmaf(acc[r], sb.x, sb.y), 0.f);
                        rm[m][r] = fmaxf(rm[m][r], v);
                    }
                }
            }
            #pragma unroll
            for (int m = 0; m < 4; ++m) {
                #pragma unroll
                for (int r = 0; r < 4; ++r) {
                    float v = rm[m][r];
                    v = fmaxf(v, __shfl_xor(v, 1));
                    v = fmaxf(v, __shfl_xor(v, 2));
                    v = fmaxf(v, __shfl_xor(v, 4));
                    v = fmaxf(v, __shfl_xor(v, 8));
                    if (l15 == 0) {
                        int ch = (wv*4+m)*16 + q*4 + r;
                        out[((b*256 + ch)*1024 + s)*4 + d] = v;
                    }
                }
            }
        }
        __syncthreads();
    }
}

extern "C" void kernel_launch(void* const* d_in, const int* in_sizes, int n_in,
                              void* d_out, int out_size, void* d_ws, size_t ws_size,
                              hipStream_t stream) {
    (void)in_sizes; (void)n_in; (void)out_size; (void)ws_size;
    const float* seed = (const float*)d_in[0];
    const float* pc   = (const float*)d_in[1];
    const float* rot  = (const float*)d_in[2];
    const float* w1   = (const float*)d_in[3];
    const float* g1   = (const float*)d_in[4];
    const float* be1  = (const float*)d_in[5];
    const float* mn1  = (const float*)d_in[6];
    const float* vr1  = (const float*)d_in[7];
    const float* w2   = (const float*)d_in[8];
    const float* g2   = (const float*)d_in[9];
    const float* be2  = (const float*)d_in[10];
    const float* mn2  = (const float*)d_in[11];
    const float* vr2  = (const float*)d_in[12];
    const float* w3   = (const float*)d_in[13];
    const float* g3   = (const float*)d_in[14];
    const float* be3  = (const float*)d_in[15];
    const float* mn3  = (const float*)d_in[16];
    const float* vr3  = (const float*)d_in[17];

    char* ws = (char*)d_ws;
    float4*       binned  = (float4*)(ws + WS_BINNED);
    unsigned int* counts  = (unsigned int*)(ws + WS_COUNTS);
    unsigned int* offsets = (unsigned int*)(ws + WS_OFFSETS);
    unsigned int* cursors = (unsigned int*)(ws + WS_CURSORS);

    zero_kernel   <<<dim3(4),    dim3(256), 0, stream>>>(counts, cursors);
    count_kernel  <<<dim3(157),  dim3(256), 0, stream>>>(pc, counts);
    prefix_kernel <<<dim3(2),    dim3(512), 0, stream>>>(counts, offsets, cursors);
    scatter_kernel<<<dim3(157),  dim3(256), 0, stream>>>(pc, cursors, binned);
    fused_kernel  <<<dim3(2048), dim3(256), 0, stream>>>(
        seed, pc, rot, counts, offsets, binned,
        w1, g1, be1, mn1, vr1,
        w2, g2, be2, mn2, vr2,
        w3, g3, be3, mn3, vr3,
        (float*)d_out);
}